// Round 4
// baseline (499.654 us; speedup 1.0000x reference)
//
#include <hip/hip_runtime.h>
#include <math.h>

namespace {

typedef __attribute__((ext_vector_type(8))) short bf16x8;
typedef __attribute__((ext_vector_type(4))) float f32x4;

constexpr int B = 16, V = 325, T = 12, F = 64, K = 4, G = 3;
constexpr int D = T * F;                   // 768
constexpr int ATT_R = 336;                 // padded rows (325 -> 336 = 21*16)
constexpr int ATT_S = 192;                 // padded K dim (163 -> 192 = 6*32), bf16
constexpr int OUT0 = B * V * T * F;        // 3,993,600 floats (gc_act)
constexpr int HT_SZ = G * K * 2 * V * F;   // 499,200 floats
constexpr float SLOPE_ = 325.0f;
constexpr float NEGINF = -9.0e15f;

// workspace layout (bytes)
constexpr size_t HT_BYTES   = (size_t)HT_SZ * 4;                  // 1,996,800
constexpr size_t ATT_BYTES  = (size_t)24 * ATT_R * ATT_S * 2;     // 3,096,576
constexpr size_t PART_OFF_B = HT_BYTES + ATT_BYTES;               // 5,093,376
constexpr size_t PART_BYTES = (size_t)6 * 192 * 336 * 64 * 4;     // 99,090,432
constexpr size_t WS_NEED    = PART_OFF_B + PART_BYTES;

__device__ __forceinline__ float leaky(float x) { return x >= 0.0f ? x : SLOPE_ * x; }

__device__ __forceinline__ unsigned short f2bf(float f) {
  unsigned int u = __float_as_uint(f);
  u = (u + 0x7fffu + ((u >> 16) & 1u)) >> 16;   // RNE
  return (unsigned short)u;
}
__device__ __forceinline__ float bf2f(unsigned short h) {
  return __uint_as_float((unsigned int)h << 16);
}

__device__ __forceinline__ float wsum(float v) {
#pragma unroll
  for (int m = 32; m >= 1; m >>= 1) v += __shfl_xor(v, m);
  return v;
}
__device__ __forceinline__ float wmax(float v) {
#pragma unroll
  for (int m = 32; m >= 1; m >>= 1) v = fmaxf(v, __shfl_xor(v, m));
  return v;
}

// ---------------------------------------------------------------------------
// K1: cluster[g,b,v,k] = softmax_k( dot(xv[b,v,:768], cw[g,k,:768]) )
// ---------------------------------------------------------------------------
__global__ __launch_bounds__(256) void k_cluster(const float* __restrict__ x,
                                                 const float* __restrict__ cw,
                                                 float* __restrict__ out) {
  const int bv = blockIdx.x;
  const int lane = threadIdx.x & 63, wave = threadIdx.x >> 6;
  __shared__ float lg[12];
  const float* xr = x + bv * D;
  for (int p = wave; p < 12; p += 4) {
    const float* wr = cw + p * D;
    float s = 0.f;
#pragma unroll
    for (int m = 0; m < 12; ++m) {
      const int d = lane + 64 * m;
      s = fmaf(xr[d], wr[d], s);
    }
    s = wsum(s);
    if (lane == 0) lg[p] = s;
  }
  __syncthreads();
  if (threadIdx.x < 3) {
    const int g = threadIdx.x;
    float m = lg[g * 4];
    for (int k = 1; k < 4; ++k) m = fmaxf(m, lg[g * 4 + k]);
    float e[4], s = 0.f;
    for (int k = 0; k < 4; ++k) { e[k] = expf(lg[g * 4 + k] - m); s += e[k]; }
    const float inv = 1.f / s;
    const int b = bv / V, v = bv % V;
    float* o = out + OUT0 + ((g * B + b) * V + v) * K;
    for (int k = 0; k < 4; ++k) o[k] = e[k] * inv;
  }
}

// ---------------------------------------------------------------------------
// K2 (MFMA, split-bf16 compensated) — unchanged from R3.
// ---------------------------------------------------------------------------
__global__ __launch_bounds__(512, 4) void k_ht(const float* __restrict__ x,
                                               const float* __restrict__ W,
                                               const float* __restrict__ Wbias,
                                               const float* __restrict__ Wt,
                                               float* __restrict__ ht) {
  const int v = blockIdx.x;
  const int tid = threadIdx.x;
  const int lane = tid & 63;
  const int wv = tid >> 6;
  const int lr = lane & 15, lg = lane >> 4;
  const int n = wv & 3, half = wv >> 2;

  __shared__ unsigned short Xhi[192 * 64];
  __shared__ unsigned short Xlo[192 * 64];
  __shared__ unsigned short Whi[64 * 64];
  __shared__ unsigned short Wlo[64 * 64];
  __shared__ float biasl[64];
  __shared__ float Wtl[12];
  __shared__ float red[4][2][16];

  for (int idx = tid; idx < 192 * 8; idx += 512) {
    const int row = idx >> 3, c0 = (idx & 7) * 8;
    const int bb = row / 12, tt = row % 12;
    const float* xp = x + ((bb * V + v) * T + tt) * F + c0;
    const float4 x0 = *(const float4*)xp;
    const float4 x1 = *(const float4*)(xp + 4);
    const float vals[8] = {x0.x, x0.y, x0.z, x0.w, x1.x, x1.y, x1.z, x1.w};
    union { unsigned short u[8]; uint4 q; } H, L;
#pragma unroll
    for (int e = 0; e < 8; ++e) {
      const unsigned short hh = f2bf(vals[e]);
      H.u[e] = hh;
      L.u[e] = f2bf(vals[e] - bf2f(hh));
    }
    const int off = (row * 128 + c0 * 2) ^ ((row & 7) << 4);
    *(uint4*)((char*)Xhi + off) = H.q;
    *(uint4*)((char*)Xlo + off) = L.q;
  }

  for (int gko = 0; gko < 24; ++gko) {
    {
      const int f = tid >> 3, c0 = (tid & 7) * 8;
      const float* wp = W + gko * (F * F) + f * 64 + c0;
      const float4 w0 = *(const float4*)wp;
      const float4 w1 = *(const float4*)(wp + 4);
      const float vals[8] = {w0.x, w0.y, w0.z, w0.w, w1.x, w1.y, w1.z, w1.w};
      union { unsigned short u[8]; uint4 q; } H, L;
#pragma unroll
      for (int e = 0; e < 8; ++e) {
        const unsigned short hh = f2bf(vals[e]);
        H.u[e] = hh;
        L.u[e] = f2bf(vals[e] - bf2f(hh));
      }
      const int off = (f * 128 + c0 * 2) ^ ((f & 7) << 4);
      *(uint4*)((char*)Whi + off) = H.q;
      *(uint4*)((char*)Wlo + off) = L.q;
      if (tid < 64) biasl[tid] = Wbias[gko * 64 + tid];
      else if (tid < 76) Wtl[tid - 64] = Wt[gko * 12 + (tid - 64)];
    }
    __syncthreads();

    float psum = 0.f;
    const float bv = biasl[n * 16 + lr];
    const int offB0 = ((n * 16 + lr) * 128) ^ (((n * 16 + lr) & 7) << 4);
#pragma unroll
    for (int i = 0; i < 6; ++i) {
      const int mt = half * 6 + i;
      const int arow = mt * 16 + lr;
      const int offA0 = (arow * 128) ^ ((arow & 7) << 4);
      f32x4 acc = (f32x4){0.f, 0.f, 0.f, 0.f};
#pragma unroll
      for (int kst = 0; kst < 2; ++kst) {
        const int kb = (kst * 32 + lg * 8) * 2;
        const bf16x8 ah = *(const bf16x8*)((const char*)Xhi + (offA0 ^ kb));
        const bf16x8 al = *(const bf16x8*)((const char*)Xlo + (offA0 ^ kb));
        const bf16x8 bh = *(const bf16x8*)((const char*)Whi + (offB0 ^ kb));
        const bf16x8 bl = *(const bf16x8*)((const char*)Wlo + (offB0 ^ kb));
        acc = __builtin_amdgcn_mfma_f32_16x16x32_bf16(ah, bh, acc, 0, 0, 0);
        acc = __builtin_amdgcn_mfma_f32_16x16x32_bf16(ah, bl, acc, 0, 0, 0);
        acc = __builtin_amdgcn_mfma_f32_16x16x32_bf16(al, bh, acc, 0, 0, 0);
      }
#pragma unroll
      for (int r = 0; r < 4; ++r) {
        const int row = mt * 16 + lg * 4 + r;
        psum = fmaf(leaky(acc[r] + bv), Wtl[row % 12], psum);
      }
    }
    psum += __shfl_xor(psum, 16);
    psum += __shfl_xor(psum, 32);
    if (lg == 0) red[n][half][lr] = psum;
    __syncthreads();
    if (tid < 64)
      ht[(gko * V + v) * 64 + tid] =
          (red[tid >> 4][0][tid & 15] + red[tid >> 4][1][tid & 15]) * (1.0f / 16.0f);
    __syncthreads();
  }
}

// ---------------------------------------------------------------------------
// K3: masked softmax -> bf16 att, padded [336][192]. Unchanged from R3.
// ---------------------------------------------------------------------------
__global__ __launch_bounds__(256) void k_att(const float* __restrict__ ht,
                                             const float* __restrict__ a,
                                             const int* __restrict__ adj,
                                             unsigned short* __restrict__ att) {
  const int gko = blockIdx.x;
  const int o = gko & 1;
  const int g = gko >> 3;
  const int Vs = o ? 162 : 163;
  const int tid = threadIdx.x, lane = tid & 63, wave = tid >> 6;
  __shared__ float s1[163], s2[325];
  const float* htg = ht + gko * (V * F);
  const float* a1 = a + gko * 128;
  const float* a2 = a1 + 64;

  for (int d = wave; d < 325 + Vs; d += 4) {
    int row; const float* av;
    if (d < 325) { row = d;                 av = a2; }
    else         { row = o + 2 * (d - 325); av = a1; }
    float s = htg[row * 64 + lane] * av[lane];
    s = wsum(s);
    if (lane == 0) { if (d < 325) s2[d] = s; else s1[d - 325] = s; }
  }
  __syncthreads();

  const int* adjg = adj + g * (V * V);
  for (int i = wave; i < V; i += 4) {
    const float e0 = s2[i];
    float vj[3];
    float mx = NEGINF;
#pragma unroll
    for (int r = 0; r < 3; ++r) {
      const int j = lane + 64 * r;
      float val = NEGINF;
      if (j < Vs) {
        const float e = leaky(s1[j] + e0);
        const int ad = adjg[i * V + (o + 2 * j)];
        val = (ad > 0) ? e : NEGINF;
      }
      vj[r] = val;
      mx = fmaxf(mx, val);
    }
    mx = wmax(mx);
    float sum = 0.f, ex[3];
#pragma unroll
    for (int r = 0; r < 3; ++r) {
      const int j = lane + 64 * r;
      const float tt = (j < Vs) ? expf(vj[r] - mx) : 0.f;
      ex[r] = tt; sum += tt;
    }
    sum = wsum(sum);
    const float inv = 1.f / sum;
    unsigned short* ar = att + ((size_t)gko * ATT_R + i) * ATT_S;
#pragma unroll
    for (int r = 0; r < 3; ++r) {
      const int j = lane + 64 * r;
      ar[j] = (j < Vs) ? f2bf(ex[r] * inv) : 0;
    }
  }
  unsigned short* zb = att + ((size_t)gko * ATT_R + 325) * ATT_S;
  for (int idx = tid; idx < (ATT_R - V) * ATT_S; idx += 256) zb[idx] = 0;
}

// ---------------------------------------------------------------------------
// K4 (MFMA): per block (g,o,b,t), loop k:
//   H-build (W B-frags in REGISTERS, prefetched; n = wv&3 is wave-constant)
//   C-GEMM att x H, epilogue accO += leaky(hp)*cl.
// Output: plain stores to partial[g*2+o] if part != nullptr, else atomicAdd.
// 2 barriers per k (W-stage phase eliminated).
// ---------------------------------------------------------------------------
__global__ __launch_bounds__(512, 4) void k_hp(const float* __restrict__ x,
                                               const float* __restrict__ W,
                                               const float* __restrict__ Wbias,
                                               const unsigned short* __restrict__ att,
                                               const float* __restrict__ cluster,
                                               float* __restrict__ out,
                                               float* __restrict__ part) {
  const int bid = blockIdx.x;
  const int o = bid & 1;
  const int g = (bid >> 1) % 3;
  const int bt = bid / 6;
  const int t = bt % 12;
  const int b = bt / 12;
  const int Vs = o ? 162 : 163;
  const int tid = threadIdx.x;
  const int lane = tid & 63;
  const int wv = tid >> 6;       // 8 waves
  const int lr = lane & 15;
  const int lg = lane >> 4;
  const int n = wv & 3;          // wave-constant N-tile in H-build
  const int halfw = wv >> 2;

  __shared__ unsigned short Xl[176 * 64];    // 22.5 KB, swizzled
  __shared__ unsigned short Htl[64 * 192];   // 24.6 KB, swizzled
  __shared__ float cll[336 * 4];             // 5.4 KB

  // ---- stage X as bf16 (rows >= Vs zero), swizzled ----
  for (int idx = tid; idx < 176 * 8; idx += 512) {
    const int j = idx >> 3, c0 = (idx & 7) * 8;
    union { unsigned short u[8]; uint4 q; } P;
    if (j < Vs) {
      const float* xp = x + ((b * V + (o + 2 * j)) * T + t) * F + c0;
      const float4 x0 = *(const float4*)xp;
      const float4 x1 = *(const float4*)(xp + 4);
      P.u[0] = f2bf(x0.x); P.u[1] = f2bf(x0.y); P.u[2] = f2bf(x0.z); P.u[3] = f2bf(x0.w);
      P.u[4] = f2bf(x1.x); P.u[5] = f2bf(x1.y); P.u[6] = f2bf(x1.z); P.u[7] = f2bf(x1.w);
    } else {
      P.q = make_uint4(0, 0, 0, 0);
    }
    *(uint4*)((char*)Xl + ((j * 128 + c0 * 2) ^ ((j & 7) << 4))) = P.q;
  }
  // ---- stage cluster weights ----
  for (int i = tid; i < 336; i += 512) {
    float4 c4 = make_float4(0.f, 0.f, 0.f, 0.f);
    if (i < V) c4 = *(const float4*)(cluster + ((g * B + b) * V + i) * K);
    *(float4*)&cll[i * 4] = c4;
  }
  // ---- zero Htl K-pad cols 176..191 (through the swizzle) ----
  if (tid < 128) {
    const int f = tid >> 1, j0 = 176 + (tid & 1) * 8;
    *(uint4*)((char*)Htl + ((f * 384 + j0 * 2) ^ ((f & 7) << 4))) = make_uint4(0, 0, 0, 0);
  }

  // ---- W fragment prefetch for k=0 (per-wave registers) ----
  const int f_row = n * 16 + lr;
  float4 praw[2][2];
  float bias_now;
  {
    const int gko0 = (g * K + 0) * 2 + o;
    const float* wp = W + gko0 * (F * F) + f_row * 64 + lg * 8;
#pragma unroll
    for (int kst = 0; kst < 2; ++kst) {
      praw[kst][0] = *(const float4*)(wp + kst * 32);
      praw[kst][1] = *(const float4*)(wp + kst * 32 + 4);
    }
    bias_now = Wbias[gko0 * 64 + f_row];
  }

  f32x4 accO[3][4];
#pragma unroll
  for (int s = 0; s < 3; ++s)
#pragma unroll
    for (int nn = 0; nn < 4; ++nn) accO[s][nn] = (f32x4){0.f, 0.f, 0.f, 0.f};

  for (int k = 0; k < K; ++k) {
    const int gko = (g * K + k) * 2 + o;
    __syncthreads();  // k=0: X staged; k>0: prev C-GEMM done reading Htl

    // ---- convert prefetched W to bf16 frags ----
    bf16x8 wf[2];
#pragma unroll
    for (int kst = 0; kst < 2; ++kst) {
      const float vals[8] = {praw[kst][0].x, praw[kst][0].y, praw[kst][0].z, praw[kst][0].w,
                             praw[kst][1].x, praw[kst][1].y, praw[kst][1].z, praw[kst][1].w};
      union { unsigned short u[8]; bf16x8 v; } P;
#pragma unroll
      for (int e = 0; e < 8; ++e) P.u[e] = f2bf(vals[e]);
      wf[kst] = P.v;
    }
    const float bnow = bias_now;

    // ---- H-build: wave does fixed n; mt = halfw + 2s ----
#pragma unroll
    for (int s = 0; s < 6; ++s) {
      const int mt = halfw + 2 * s;
      if (mt < 11) {
        f32x4 acc = (f32x4){0.f, 0.f, 0.f, 0.f};
#pragma unroll
        for (int kst = 0; kst < 2; ++kst) {
          const int j = mt * 16 + lr, k0 = kst * 32 + lg * 8;
          const bf16x8 af = *(const bf16x8*)((const char*)Xl + ((j * 128 + k0 * 2) ^ ((j & 7) << 4)));
          acc = __builtin_amdgcn_mfma_f32_16x16x32_bf16(af, wf[kst], acc, 0, 0, 0);
        }
        const int j0 = mt * 16 + lg * 4;
        union { unsigned short u[4]; uint2 q; } Pk;
#pragma unroll
        for (int r = 0; r < 4; ++r) {
          const float val = leaky(acc[r] + bnow);
          Pk.u[r] = (j0 + r < Vs) ? f2bf(val) : 0;
        }
        *(uint2*)((char*)Htl + ((f_row * 384 + j0 * 2) ^ ((f_row & 7) << 4))) = Pk.q;
      }
    }

    // ---- prefetch W for k+1 (hidden under C-GEMM) ----
    if (k < 3) {
      const int gkon = (g * K + (k + 1)) * 2 + o;
      const float* wp = W + gkon * (F * F) + f_row * 64 + lg * 8;
#pragma unroll
      for (int kst = 0; kst < 2; ++kst) {
        praw[kst][0] = *(const float4*)(wp + kst * 32);
        praw[kst][1] = *(const float4*)(wp + kst * 32 + 4);
      }
      bias_now = Wbias[gkon * 64 + f_row];
    }
    __syncthreads();  // Htl written

    // ---- C-GEMM: acc[i,f] = att[i,:] x H[:,f] ----
    f32x4 accC[3][4];
#pragma unroll
    for (int s = 0; s < 3; ++s)
#pragma unroll
      for (int nn = 0; nn < 4; ++nn) accC[s][nn] = (f32x4){0.f, 0.f, 0.f, 0.f};

    const unsigned short* ab = att + (size_t)gko * (ATT_R * ATT_S);
#pragma unroll
    for (int kst = 0; kst < 6; ++kst) {
      const int kk0 = kst * 32 + lg * 8;
      bf16x8 bfr[4];
#pragma unroll
      for (int nn = 0; nn < 4; ++nn) {
        const int f = nn * 16 + lr;
        bfr[nn] = *(const bf16x8*)((const char*)Htl + ((f * 384 + kk0 * 2) ^ ((f & 7) << 4)));
      }
#pragma unroll
      for (int s = 0; s < 3; ++s) {
        const int mt = wv + 8 * s;
        if (mt < 21) {
          const bf16x8 af = *(const bf16x8*)(ab + (mt * 16 + lr) * ATT_S + kk0);
#pragma unroll
          for (int nn = 0; nn < 4; ++nn)
            accC[s][nn] = __builtin_amdgcn_mfma_f32_16x16x32_bf16(af, bfr[nn], accC[s][nn], 0, 0, 0);
        }
      }
    }
    // ---- epilogue: accO += leaky(hp) * cl[k] ----
#pragma unroll
    for (int s = 0; s < 3; ++s) {
      const int mt = wv + 8 * s;
      if (mt < 21) {
        const int i0 = mt * 16 + lg * 4;
#pragma unroll
        for (int r = 0; r < 4; ++r) {
          const float clv = cll[(i0 + r) * 4 + k];
#pragma unroll
          for (int nn = 0; nn < 4; ++nn)
            accO[s][nn][r] += leaky(accC[s][nn][r]) * clv;
        }
      }
    }
  }

  // ---- output: plain partial stores (no atomics) or atomic fallback ----
  if (part) {
    float* pb = part + (((size_t)(g * 2 + o) * 192 + bt) * 336) * 64;
#pragma unroll
    for (int s = 0; s < 3; ++s) {
      const int mt = wv + 8 * s;
      if (mt < 21) {
        const int i0 = mt * 16 + lg * 4;
#pragma unroll
        for (int r = 0; r < 4; ++r) {
          float* op = pb + (i0 + r) * 64 + lr;
#pragma unroll
          for (int nn = 0; nn < 4; ++nn) op[nn * 16] = accO[s][nn][r];
        }
      }
    }
  } else {
#pragma unroll
    for (int s = 0; s < 3; ++s) {
      const int mt = wv + 8 * s;
      if (mt < 21) {
        const int i0 = mt * 16 + lg * 4;
#pragma unroll
        for (int r = 0; r < 4; ++r) {
          const int i = i0 + r;
          if (i < V) {
            float* op = out + ((b * V + i) * T + t) * F + lr;
#pragma unroll
            for (int nn = 0; nn < 4; ++nn)
              atomicAdd(op + nn * 16, accO[s][nn][r] * (1.0f / 3.0f));
          }
        }
      }
    }
  }
}

// ---------------------------------------------------------------------------
// K5: out[b,v,t,f] = (1/3) * sum_{p<6} partial[p][b,t,v,f]. One float4/thread.
// ---------------------------------------------------------------------------
__global__ __launch_bounds__(256) void k_red(const float* __restrict__ part,
                                             float* __restrict__ out) {
  const int idx = blockIdx.x * 256 + threadIdx.x;   // float4 index
  const int f4 = idx & 15;
  const int r = idx >> 4;
  const int t = r % T;
  const int r2 = r / T;
  const int v = r2 % V;
  const int b = r2 / V;
  const size_t base = (((size_t)(b * T + t)) * 336 + v) * 16 + f4;
  f32x4 s = (f32x4){0.f, 0.f, 0.f, 0.f};
#pragma unroll
  for (int p = 0; p < 6; ++p) {
    const float4 q = *(const float4*)(part + (base + (size_t)p * 192 * 336 * 16) * 4);
    s[0] += q.x; s[1] += q.y; s[2] += q.z; s[3] += q.w;
  }
  float4 o4;
  o4.x = s[0] * (1.0f / 3.0f); o4.y = s[1] * (1.0f / 3.0f);
  o4.z = s[2] * (1.0f / 3.0f); o4.w = s[3] * (1.0f / 3.0f);
  *(float4*)(out + (size_t)idx * 4) = o4;
}

}  // namespace

extern "C" void kernel_launch(void* const* d_in, const int* in_sizes, int n_in,
                              void* d_out, int out_size, void* d_ws, size_t ws_size,
                              hipStream_t stream) {
  const float* x   = (const float*)d_in[0];
  const int*   adj = (const int*)d_in[1];
  const float* W   = (const float*)d_in[2];
  const float* Wb  = (const float*)d_in[3];
  const float* Wt  = (const float*)d_in[4];
  const float* a   = (const float*)d_in[5];
  const float* cw  = (const float*)d_in[6];
  float* out = (float*)d_out;
  char*  ws  = (char*)d_ws;

  float* ht = (float*)ws;
  unsigned short* attw = (unsigned short*)(ws + HT_BYTES);
  float* part = (ws_size >= WS_NEED) ? (float*)(ws + PART_OFF_B) : nullptr;

  if (!part) hipMemsetAsync(out, 0, (size_t)OUT0 * sizeof(float), stream);
  k_cluster<<<B * V, 256, 0, stream>>>(x, cw, out);
  k_ht<<<V, 512, 0, stream>>>(x, W, Wb, Wt, ht);
  k_att<<<G * K * 2, 256, 0, stream>>>(ht, a, adj, attw);
  k_hp<<<B * T * G * 2, 512, 0, stream>>>(x, W, Wb, attw, out + OUT0, out, part);
  if (part) k_red<<<OUT0 / 4 / 256, 256, 0, stream>>>(part, out);
}